// Round 1
// baseline (348.081 us; speedup 1.0000x reference)
//
#include <hip/hip_runtime.h>
#include <hip/hip_bf16.h>

// CGCNN: B=16, N=1024, M=12, F=64, BF=128, 3 conv layers.
// Key restructure: bond is layer-invariant, so core_l = bond @ cw3_l for ALL
// 3 layers (+ filt columns) is ONE bf16 MFMA GEMM reading bond once.
// Per-layer work = per-atom fp32 projections (atomproj) + light epilogue.
//
// R1: persistent gemm_bond — 512 blocks (2/CU, all co-resident), weights
// staged to LDS ONCE per block, then a barrier-free loop over 3x128-row
// tiles with A loaded global->reg. Weight panel columns are permuted
// (4x16 transpose per layer) so the epilogue stores packed ushort4.

#define BB 16
#define NN 1024
#define MM 12
#define FF 64
#define BFE 128
#define RT (BB * NN * MM)   // 196608 bond rows
#define S_BN 0.99950037f    // 1/sqrt(1+1e-3)
#define WCOLS 208           // 192 core cols (3 layers x 64) + 3 filt + 13 pad
#define WSTR 136            // padded K stride (bf16 elems) -> conflict-free b128

typedef __attribute__((ext_vector_type(8))) short bf16x8;
typedef __attribute__((ext_vector_type(4))) float f32x4;

static __device__ __forceinline__ unsigned short f2bf(float f) {
    union { float f; unsigned u; } c; c.f = f;
    unsigned r = c.u + 0x7fff + ((c.u >> 16) & 1);   // RNE
    return (unsigned short)(r >> 16);
}
static __device__ __forceinline__ float bf2f(unsigned short s) {
    union { unsigned u; float f; } c; c.u = ((unsigned)s) << 16;
    return c.f;
}
static __device__ __forceinline__ bf16x8 pack_bf16x8(float4 a, float4 b) {
    union { unsigned u[4]; bf16x8 v; } r;
    r.u[0] = (unsigned)f2bf(a.x) | ((unsigned)f2bf(a.y) << 16);
    r.u[1] = (unsigned)f2bf(a.z) | ((unsigned)f2bf(a.w) << 16);
    r.u[2] = (unsigned)f2bf(b.x) | ((unsigned)f2bf(b.y) << 16);
    r.u[3] = (unsigned)f2bf(b.z) | ((unsigned)f2bf(b.w) << 16);
    return r.v;
}

// ---- fold BN-a into core weights (fp32 copy, used by atomproj rows 0..127) --
__global__ void fold_w(const float* __restrict__ cw, const float* __restrict__ cb,
                       const float* __restrict__ g,  const float* __restrict__ bab,
                       float* __restrict__ cwp, float* __restrict__ cbp) {
    int i = blockIdx.x * 256 + threadIdx.x;           // 3*256*64
    if (i >= 3 * 256 * 64) return;
    int f = i & 63;
    int l = i / (256 * 64);
    float gs = g[l * 64 + f] * S_BN;
    cwp[i] = cw[i] * gs;
    if (((i >> 6) & 255) == 0)
        cbp[l * 64 + f] = cb[l * 64 + f] * gs + bab[l * 64 + f];
}

// ---- build transposed bf16 weight panel wT[col][k] for the bond GEMM -------
// Column order is PERMUTED per layer so the GEMM epilogue can store packed
// ushort4: panel col l*64 + p (p = tt*16 + m) holds feature f = 4*m + tt.
// cols 192..194: filt_w rows 128..255 for layer col-192; rest zero pad.
__global__ void prep_wT(const float* __restrict__ cw, const float* __restrict__ g,
                        const float* __restrict__ fw, unsigned short* __restrict__ wT) {
    int i = blockIdx.x * 256 + threadIdx.x;           // WCOLS*WSTR = 28288
    if (i >= WCOLS * WSTR) return;
    int col = i / WSTR, k = i % WSTR;
    float v = 0.f;
    if (k < 128) {
        if (col < 192) {
            int l = col >> 6, p = col & 63;
            int f = ((p & 15) << 2) | (p >> 4);       // 4*m + tt
            v = cw[(l * 256 + 128 + k) * 64 + f] * g[l * 64 + f] * S_BN;
        } else if (col < 195) {
            int l = col - 192;
            v = fw[l * 256 + 128 + k];
        }
    }
    wT[i] = f2bf(v);
}

// ---- embedding gather ------------------------------------------------------
__global__ void embed_k(const int* __restrict__ at, const float* __restrict__ emb,
                        float* __restrict__ x) {
    int i = blockIdx.x * 256 + threadIdx.x;
    int f = i & 63;
    int bn = i >> 6;
    x[i] = emb[at[bn] * FF + f];
}

// ---- one-shot bf16 MFMA GEMM: core_{0,1,2} (bf16) + filt_{0,1,2} (fp32) ----
// A = bond (196608 x 128, fp32 -> bf16 in registers), B = wT (128 x 208)
// 512 blocks x 3 iters x 128 rows; weights staged once, no barrier in loop.
static __device__ __forceinline__ void store_tile(
    const f32x4* acc, unsigned short* __restrict__ core,
    float* __restrict__ filt, int crow, int m) {
    #pragma unroll
    for (int l = 0; l < 3; l++) {
        #pragma unroll
        for (int r = 0; r < 4; r++) {
            ushort4 h;
            h.x = f2bf(acc[l * 4 + 0][r]);
            h.y = f2bf(acc[l * 4 + 1][r]);
            h.z = f2bf(acc[l * 4 + 2][r]);
            h.w = f2bf(acc[l * 4 + 3][r]);
            *(ushort4*)&core[((size_t)l * RT + crow + r) * 64 + 4 * m] = h;
        }
    }
    if (m < 3) {
        #pragma unroll
        for (int r = 0; r < 4; r++)
            filt[(size_t)m * RT + crow + r] = acc[12][r];
    }
}

__global__ __launch_bounds__(256, 2) void gemm_bond(
    const float* __restrict__ bond, const unsigned short* __restrict__ wT,
    unsigned short* __restrict__ core, float* __restrict__ filt) {
    __shared__ unsigned short bsh[WCOLS * WSTR];  // 56576 B weights
    int tid = threadIdx.x;
    int w = tid >> 6, lane = tid & 63;
    int m = lane & 15, quad = lane >> 4;

    // stage weights ONCE (3536 float4)
    const float4* wsrc = (const float4*)wT;
    float4* wdst = (float4*)bsh;
    #pragma unroll
    for (int i = 0; i < 14; i++) {
        int idx = tid + 256 * i;
        if (idx < (WCOLS * WSTR * 2) / 16) wdst[idx] = wsrc[idx];
    }
    __syncthreads();

    #pragma unroll 1
    for (int it = 0; it < 3; it++) {
        int row0 = blockIdx.x * 384 + it * 128;
        // wave w owns rows [row0 + w*32, +32): two 16-row MFMA fragments
        const float* abase = bond + (size_t)(row0 + w * 32 + m) * BFE + quad * 8;

        // load A for this 128-row tile: 16 float4 per lane
        float4 areg[16];
        #pragma unroll
        for (int fr = 0; fr < 2; fr++) {
            #pragma unroll
            for (int c = 0; c < 4; c++) {
                areg[fr * 8 + c * 2 + 0] = *(const float4*)(abase + fr * 16 * BFE + c * 32);
                areg[fr * 8 + c * 2 + 1] = *(const float4*)(abase + fr * 16 * BFE + c * 32 + 4);
            }
        }
        bf16x8 af[2][4];
        #pragma unroll
        for (int fr = 0; fr < 2; fr++)
            #pragma unroll
            for (int c = 0; c < 4; c++)
                af[fr][c] = pack_bf16x8(areg[fr * 8 + c * 2], areg[fr * 8 + c * 2 + 1]);

        f32x4 acc0[13], acc1[13];
        #pragma unroll
        for (int t = 0; t < 13; t++) {
            acc0[t] = (f32x4){0.f, 0.f, 0.f, 0.f};
            acc1[t] = (f32x4){0.f, 0.f, 0.f, 0.f};
        }

        #pragma unroll
        for (int c = 0; c < 4; c++) {
            bf16x8 a0 = af[0][c], a1 = af[1][c];
            #pragma unroll
            for (int t = 0; t < 13; t++) {
                bf16x8 bfv = *(const bf16x8*)&bsh[(t * 16 + m) * WSTR + c * 32 + quad * 8];
                acc0[t] = __builtin_amdgcn_mfma_f32_16x16x32_bf16(a0, bfv, acc0[t], 0, 0, 0);
                acc1[t] = __builtin_amdgcn_mfma_f32_16x16x32_bf16(a1, bfv, acc1[t], 0, 0, 0);
            }
        }

        // epilogue: lane m's 4 acc tiles per layer are features 4m..4m+3
        int crow = row0 + w * 32 + quad * 4;
        store_tile(acc0, core, filt, crow, m);
        store_tile(acc1, core, filt, crow + 16, m);
    }
}

// ---- per-atom projections (persistent LDS weights) -------------------------
__global__ __launch_bounds__(256) void atomproj(
    const float* __restrict__ x, const float* __restrict__ cwp_l,
    const float* __restrict__ cbp_l, const float* __restrict__ fw_l,
    const float* __restrict__ fb_l,
    float* __restrict__ ys, float* __restrict__ yn,
    float* __restrict__ fs, float* __restrict__ fn) {
    __shared__ float wsh[128 * 64];   // 32 KB: folded cw rows 0..127
    __shared__ float xs[4][64];
    int tid = threadIdx.x, w = tid >> 6, lane = tid & 63;
    #pragma unroll
    for (int i = 0; i < 8; i++)
        ((float4*)wsh)[tid + 256 * i] = ((const float4*)cwp_l)[tid + 256 * i];
    float fw1 = fw_l[lane], fw2 = fw_l[64 + lane];
    float cb = cbp_l[lane], fbv = fb_l[0];
    __syncthreads();
    #pragma unroll 1
    for (int it = 0; it < 4; it++) {
        int row = (blockIdx.x * 4 + it) * 4 + w;      // grid 1024 -> 16384 rows
        float xl = x[(size_t)row * 64 + lane];
        xs[w][lane] = xl;                              // wave-private tile
        float a1 = cb, a2 = 0.f;
        #pragma unroll 16
        for (int k = 0; k < 64; k++) {
            float xv = xs[w][k];
            a1 += xv * wsh[k * 64 + lane];
            a2 += xv * wsh[(64 + k) * 64 + lane];
        }
        ys[(size_t)row * 64 + lane] = a1;
        yn[(size_t)row * 64 + lane] = a2;
        float p1 = xl * fw1, p2 = xl * fw2;
        #pragma unroll
        for (int off = 32; off; off >>= 1) {
            p1 += __shfl_xor(p1, off, 64);
            p2 += __shfl_xor(p2, off, 64);
        }
        if (lane == 0) { fs[row] = p1 + fbv; fn[row] = p2; }
    }
}

// ---- per-layer epilogue: softmax + weighted mean + BN-b + residual ---------
__global__ __launch_bounds__(256) void layer_ep(
    const float* __restrict__ x, const unsigned short* __restrict__ core_l,
    const float* __restrict__ filt_l, const int* __restrict__ nbr,
    const float* __restrict__ ys, const float* __restrict__ yn,
    const float* __restrict__ fs, const float* __restrict__ fn,
    const float* __restrict__ bbg, const float* __restrict__ bbb,
    float* __restrict__ xout) {
    int tid = threadIdx.x, w = tid >> 6, lane = tid & 63;
    int row = blockIdx.x * 4 + w;
    int base = (row >> 10) * NN;
    size_t rb = (size_t)row * MM;

    int jv[MM]; float fltv[MM], corev[MM];
    #pragma unroll
    for (int mm = 0; mm < MM; mm++) jv[mm] = nbr[rb + mm];
    float fsv = fs[row], ysv = ys[(size_t)row * 64 + lane];
    #pragma unroll
    for (int mm = 0; mm < MM; mm++)
        fltv[mm] = filt_l[rb + mm] + fsv + fn[base + jv[mm]];
    #pragma unroll
    for (int mm = 0; mm < MM; mm++)
        corev[mm] = bf2f(core_l[(rb + mm) * 64 + lane]) + ysv
                  + yn[(size_t)(base + jv[mm]) * 64 + lane];
    float fmax = -1e30f;
    #pragma unroll
    for (int mm = 0; mm < MM; mm++) fmax = fmaxf(fmax, fltv[mm]);
    float fsum = 0.f;
    #pragma unroll
    for (int mm = 0; mm < MM; mm++) { fltv[mm] = __expf(fltv[mm] - fmax); fsum += fltv[mm]; }
    float inv = 1.f / (12.f * fsum);
    float summed = 0.f;
    #pragma unroll
    for (int mm = 0; mm < MM; mm++) summed += fltv[mm] * fmaxf(corev[mm], 0.f);
    summed *= inv;
    float o = x[(size_t)row * 64 + lane] + bbg[lane] * (summed * S_BN) + bbb[lane];
    xout[(size_t)row * 64 + lane] = fmaxf(o, 0.f);
}

// ---- pooling gather + dense + relu ----------------------------------------
__global__ __launch_bounds__(256) void final_k(
    const float* __restrict__ x, const int* __restrict__ tidx,
    const float* __restrict__ dw, const float* __restrict__ db,
    float* __restrict__ out) {
    __shared__ float xs[4][64];
    __shared__ float wsh[64 * 64];
    int tid = threadIdx.x;
    int w = tid >> 6, lane = tid & 63;
    const float4* src = (const float4*)dw;
    float4* dst = (float4*)wsh;
    #pragma unroll
    for (int i = 0; i < 4; i++) dst[tid + 256 * i] = src[tid + 256 * i];
    int row = blockIdx.x * 4 + w;        // b*64 + i
    int b = row >> 6;
    int t = tidx[row];
    float xv = x[((size_t)b * NN + t) * 64 + lane];
    xs[w][lane] = fmaxf(xv, 0.f);
    __syncthreads();
    float a = db[lane];
    #pragma unroll 16
    for (int k = 0; k < 64; k++) a += xs[w][k] * wsh[k * 64 + lane];
    out[row * 64 + lane] = fmaxf(a, 0.f);
}

extern "C" void kernel_launch(void* const* d_in, const int* in_sizes, int n_in,
                              void* d_out, int out_size, void* d_ws, size_t ws_size,
                              hipStream_t stream) {
    const int*   at   = (const int*)d_in[0];
    const float* bond = (const float*)d_in[1];
    const int*   nbr  = (const int*)d_in[2];
    const int*   tgt  = (const int*)d_in[3];
    const float* emb  = (const float*)d_in[4];
    const float* cw   = (const float*)d_in[5];
    const float* cb   = (const float*)d_in[6];
    const float* fw   = (const float*)d_in[7];
    const float* fb   = (const float*)d_in[8];
    const float* bag  = (const float*)d_in[9];
    const float* bab  = (const float*)d_in[10];
    const float* bbg  = (const float*)d_in[11];
    const float* bbb  = (const float*)d_in[12];
    const float* dw   = (const float*)d_in[13];
    const float* db   = (const float*)d_in[14];

    float* ws   = (float*)d_ws;
    float* xA   = ws;
    float* xB   = xA + (size_t)BB * NN * FF;          // 1,048,576 each
    float* cwp  = xB + (size_t)BB * NN * FF;          // 49,152
    float* cbp  = cwp + 3 * 256 * 64;                 // 192
    float* ys   = cbp + 192;                          // 1,048,576
    float* yn   = ys + (size_t)BB * NN * FF;          // 1,048,576
    float* fs   = yn + (size_t)BB * NN * FF;          // 16,384
    float* fn   = fs + (size_t)BB * NN;               // 16,384
    float* filt = fn + (size_t)BB * NN;               // 3*196608 fp32
    unsigned short* wT   = (unsigned short*)(filt + 3 * (size_t)RT);  // 28,288 bf16
    unsigned short* core = wT + WCOLS * WSTR;         // 3*196608*64 bf16 (~75.5 MB)
    // total ~95 MB

    fold_w<<<(3 * 256 * 64 + 255) / 256, 256, 0, stream>>>(cw, cb, bag, bab, cwp, cbp);
    prep_wT<<<(WCOLS * WSTR + 255) / 256, 256, 0, stream>>>(cw, bag, fw, wT);
    embed_k<<<(BB * NN * FF) / 256, 256, 0, stream>>>(at, emb, xA);
    gemm_bond<<<512, 256, 0, stream>>>(bond, wT, core, filt);

    float* xin = xA;
    float* xout = xB;
    for (int l = 0; l < 3; l++) {
        atomproj<<<BB * NN / 16, 256, 0, stream>>>(
            xin, cwp + (size_t)l * 256 * 64, cbp + l * 64, fw + l * 256, fb + l,
            ys, yn, fs, fn);
        layer_ep<<<BB * NN / 4, 256, 0, stream>>>(
            xin, core + (size_t)l * RT * 64, filt + (size_t)l * RT, nbr,
            ys, yn, fs, fn, bbg + l * 64, bbb + l * 64, xout);
        float* t = xin; xin = xout; xout = t;
    }

    final_k<<<BB * 64 / 4, 256, 0, stream>>>(xin, tgt, dw, db, (float*)d_out);
}

// Round 2
// 319.190 us; speedup vs baseline: 1.0905x; 1.0905x over previous
//
#include <hip/hip_runtime.h>
#include <hip/hip_bf16.h>

// CGCNN: B=16, N=1024, M=12, F=64, BF=128, 3 conv layers.
// Key restructure: bond is layer-invariant, so core_l = bond @ cw3_l for ALL
// 3 layers (+ filt columns) is ONE bf16 MFMA GEMM reading bond once.
// Per-layer work = per-atom fp32 projections (atomproj) + light epilogue.
//
// R1: persistent gemm_bond — 512 blocks (2/CU), weights staged to LDS once,
// barrier-free loop over 3x128-row tiles, A global->reg, packed ushort4 stores.
// R2: fix R1's VGPR-spill regression (FETCH/WRITE +75MB each = scratch):
//   - A converted to bf16 at load time (no float4 staging array)
//   - accumulators split into two passes (t 0..7, then t 8..12) so peak
//     live regs ~= 32 (af) + 64 (acc) + addr < 128. Zero spill.

#define BB 16
#define NN 1024
#define MM 12
#define FF 64
#define BFE 128
#define RT (BB * NN * MM)   // 196608 bond rows
#define S_BN 0.99950037f    // 1/sqrt(1+1e-3)
#define WCOLS 208           // 192 core cols (3 layers x 64) + 3 filt + 13 pad
#define WSTR 136            // padded K stride (bf16 elems) -> conflict-free b128

typedef __attribute__((ext_vector_type(8))) short bf16x8;
typedef __attribute__((ext_vector_type(4))) float f32x4;

static __device__ __forceinline__ unsigned short f2bf(float f) {
    union { float f; unsigned u; } c; c.f = f;
    unsigned r = c.u + 0x7fff + ((c.u >> 16) & 1);   // RNE
    return (unsigned short)(r >> 16);
}
static __device__ __forceinline__ float bf2f(unsigned short s) {
    union { unsigned u; float f; } c; c.u = ((unsigned)s) << 16;
    return c.f;
}
static __device__ __forceinline__ bf16x8 pack_bf16x8(float4 a, float4 b) {
    union { unsigned u[4]; bf16x8 v; } r;
    r.u[0] = (unsigned)f2bf(a.x) | ((unsigned)f2bf(a.y) << 16);
    r.u[1] = (unsigned)f2bf(a.z) | ((unsigned)f2bf(a.w) << 16);
    r.u[2] = (unsigned)f2bf(b.x) | ((unsigned)f2bf(b.y) << 16);
    r.u[3] = (unsigned)f2bf(b.z) | ((unsigned)f2bf(b.w) << 16);
    return r.v;
}

// ---- fold BN-a into core weights (fp32 copy, used by atomproj rows 0..127) --
__global__ void fold_w(const float* __restrict__ cw, const float* __restrict__ cb,
                       const float* __restrict__ g,  const float* __restrict__ bab,
                       float* __restrict__ cwp, float* __restrict__ cbp) {
    int i = blockIdx.x * 256 + threadIdx.x;           // 3*256*64
    if (i >= 3 * 256 * 64) return;
    int f = i & 63;
    int l = i / (256 * 64);
    float gs = g[l * 64 + f] * S_BN;
    cwp[i] = cw[i] * gs;
    if (((i >> 6) & 255) == 0)
        cbp[l * 64 + f] = cb[l * 64 + f] * gs + bab[l * 64 + f];
}

// ---- build transposed bf16 weight panel wT[col][k] for the bond GEMM -------
// Column order is PERMUTED per layer so the GEMM epilogue can store packed
// ushort4: panel col l*64 + p (p = tt*16 + m) holds feature f = 4*m + tt.
// cols 192..194: filt_w rows 128..255 for layer col-192; rest zero pad.
__global__ void prep_wT(const float* __restrict__ cw, const float* __restrict__ g,
                        const float* __restrict__ fw, unsigned short* __restrict__ wT) {
    int i = blockIdx.x * 256 + threadIdx.x;           // WCOLS*WSTR = 28288
    if (i >= WCOLS * WSTR) return;
    int col = i / WSTR, k = i % WSTR;
    float v = 0.f;
    if (k < 128) {
        if (col < 192) {
            int l = col >> 6, p = col & 63;
            int f = ((p & 15) << 2) | (p >> 4);       // 4*m + tt
            v = cw[(l * 256 + 128 + k) * 64 + f] * g[l * 64 + f] * S_BN;
        } else if (col < 195) {
            int l = col - 192;
            v = fw[l * 256 + 128 + k];
        }
    }
    wT[i] = f2bf(v);
}

// ---- embedding gather ------------------------------------------------------
__global__ void embed_k(const int* __restrict__ at, const float* __restrict__ emb,
                        float* __restrict__ x) {
    int i = blockIdx.x * 256 + threadIdx.x;
    int f = i & 63;
    int bn = i >> 6;
    x[i] = emb[at[bn] * FF + f];
}

// ---- one-shot bf16 MFMA GEMM: core_{0,1,2} (bf16) + filt_{0,1,2} (fp32) ----
// A = bond (196608 x 128, fp32 -> bf16 in registers), B = wT (128 x 208)
// 512 blocks x 3 iters x 128 rows; weights staged once, no barrier in loop.
static __device__ __forceinline__ void store_core4(
    const f32x4* a, unsigned short* __restrict__ core,
    size_t lbase, int crow, int m) {
    #pragma unroll
    for (int r = 0; r < 4; r++) {
        ushort4 h;
        h.x = f2bf(a[0][r]);
        h.y = f2bf(a[1][r]);
        h.z = f2bf(a[2][r]);
        h.w = f2bf(a[3][r]);
        *(ushort4*)&core[(lbase + (size_t)(crow + r)) * 64 + 4 * m] = h;
    }
}

__global__ __launch_bounds__(256, 2) void gemm_bond(
    const float* __restrict__ bond, const unsigned short* __restrict__ wT,
    unsigned short* __restrict__ core, float* __restrict__ filt) {
    __shared__ unsigned short bsh[WCOLS * WSTR];  // 56576 B weights
    int tid = threadIdx.x;
    int w = tid >> 6, lane = tid & 63;
    int m = lane & 15, quad = lane >> 4;

    // stage weights ONCE (3536 float4)
    const float4* wsrc = (const float4*)wT;
    float4* wdst = (float4*)bsh;
    #pragma unroll
    for (int i = 0; i < 14; i++) {
        int idx = tid + 256 * i;
        if (idx < (WCOLS * WSTR * 2) / 16) wdst[idx] = wsrc[idx];
    }
    __syncthreads();

    #pragma unroll 1
    for (int it = 0; it < 3; it++) {
        int row0 = blockIdx.x * 384 + it * 128;
        // wave w owns rows [row0 + w*32, +32): two 16-row MFMA fragments
        const float* abase = bond + (size_t)(row0 + w * 32 + m) * BFE + quad * 8;

        // load + convert A: only 2 float4 live at a time -> af[2][4] = 32 VGPR
        bf16x8 af[2][4];
        #pragma unroll
        for (int fr = 0; fr < 2; fr++) {
            #pragma unroll
            for (int c = 0; c < 4; c++) {
                float4 v0 = *(const float4*)(abase + fr * 16 * BFE + c * 32);
                float4 v1 = *(const float4*)(abase + fr * 16 * BFE + c * 32 + 4);
                af[fr][c] = pack_bf16x8(v0, v1);
            }
        }

        int crow = row0 + w * 32 + quad * 4;

        // ---- pass A: t = 0..7 (layers 0,1). live acc = 64 VGPR ----
        {
            f32x4 acc0[8], acc1[8];
            #pragma unroll
            for (int t = 0; t < 8; t++) {
                acc0[t] = (f32x4){0.f, 0.f, 0.f, 0.f};
                acc1[t] = (f32x4){0.f, 0.f, 0.f, 0.f};
            }
            #pragma unroll
            for (int c = 0; c < 4; c++) {
                bf16x8 a0 = af[0][c], a1 = af[1][c];
                #pragma unroll
                for (int t = 0; t < 8; t++) {
                    bf16x8 bfv = *(const bf16x8*)&bsh[(t * 16 + m) * WSTR + c * 32 + quad * 8];
                    acc0[t] = __builtin_amdgcn_mfma_f32_16x16x32_bf16(a0, bfv, acc0[t], 0, 0, 0);
                    acc1[t] = __builtin_amdgcn_mfma_f32_16x16x32_bf16(a1, bfv, acc1[t], 0, 0, 0);
                }
            }
            store_core4(acc0 + 0, core, 0,  crow, m);
            store_core4(acc0 + 4, core, RT, crow, m);
            store_core4(acc1 + 0, core, 0,  crow + 16, m);
            store_core4(acc1 + 4, core, RT, crow + 16, m);
        }

        // ---- pass B: t = 8..12 (layer 2 + filt). live acc = 40 VGPR ----
        {
            f32x4 acc0[5], acc1[5];
            #pragma unroll
            for (int t = 0; t < 5; t++) {
                acc0[t] = (f32x4){0.f, 0.f, 0.f, 0.f};
                acc1[t] = (f32x4){0.f, 0.f, 0.f, 0.f};
            }
            #pragma unroll
            for (int c = 0; c < 4; c++) {
                bf16x8 a0 = af[0][c], a1 = af[1][c];
                #pragma unroll
                for (int t = 0; t < 5; t++) {
                    bf16x8 bfv = *(const bf16x8*)&bsh[((t + 8) * 16 + m) * WSTR + c * 32 + quad * 8];
                    acc0[t] = __builtin_amdgcn_mfma_f32_16x16x32_bf16(a0, bfv, acc0[t], 0, 0, 0);
                    acc1[t] = __builtin_amdgcn_mfma_f32_16x16x32_bf16(a1, bfv, acc1[t], 0, 0, 0);
                }
            }
            store_core4(acc0, core, 2 * (size_t)RT, crow, m);
            store_core4(acc1, core, 2 * (size_t)RT, crow + 16, m);
            if (m < 3) {
                #pragma unroll
                for (int r = 0; r < 4; r++) {
                    filt[(size_t)m * RT + crow + r] = acc0[4][r];
                    filt[(size_t)m * RT + crow + 16 + r] = acc1[4][r];
                }
            }
        }
    }
}

// ---- per-atom projections (persistent LDS weights) -------------------------
__global__ __launch_bounds__(256) void atomproj(
    const float* __restrict__ x, const float* __restrict__ cwp_l,
    const float* __restrict__ cbp_l, const float* __restrict__ fw_l,
    const float* __restrict__ fb_l,
    float* __restrict__ ys, float* __restrict__ yn,
    float* __restrict__ fs, float* __restrict__ fn) {
    __shared__ float wsh[128 * 64];   // 32 KB: folded cw rows 0..127
    __shared__ float xs[4][64];
    int tid = threadIdx.x, w = tid >> 6, lane = tid & 63;
    #pragma unroll
    for (int i = 0; i < 8; i++)
        ((float4*)wsh)[tid + 256 * i] = ((const float4*)cwp_l)[tid + 256 * i];
    float fw1 = fw_l[lane], fw2 = fw_l[64 + lane];
    float cb = cbp_l[lane], fbv = fb_l[0];
    __syncthreads();
    #pragma unroll 1
    for (int it = 0; it < 4; it++) {
        int row = (blockIdx.x * 4 + it) * 4 + w;      // grid 1024 -> 16384 rows
        float xl = x[(size_t)row * 64 + lane];
        xs[w][lane] = xl;                              // wave-private tile
        float a1 = cb, a2 = 0.f;
        #pragma unroll 16
        for (int k = 0; k < 64; k++) {
            float xv = xs[w][k];
            a1 += xv * wsh[k * 64 + lane];
            a2 += xv * wsh[(64 + k) * 64 + lane];
        }
        ys[(size_t)row * 64 + lane] = a1;
        yn[(size_t)row * 64 + lane] = a2;
        float p1 = xl * fw1, p2 = xl * fw2;
        #pragma unroll
        for (int off = 32; off; off >>= 1) {
            p1 += __shfl_xor(p1, off, 64);
            p2 += __shfl_xor(p2, off, 64);
        }
        if (lane == 0) { fs[row] = p1 + fbv; fn[row] = p2; }
    }
}

// ---- per-layer epilogue: softmax + weighted mean + BN-b + residual ---------
__global__ __launch_bounds__(256) void layer_ep(
    const float* __restrict__ x, const unsigned short* __restrict__ core_l,
    const float* __restrict__ filt_l, const int* __restrict__ nbr,
    const float* __restrict__ ys, const float* __restrict__ yn,
    const float* __restrict__ fs, const float* __restrict__ fn,
    const float* __restrict__ bbg, const float* __restrict__ bbb,
    float* __restrict__ xout) {
    int tid = threadIdx.x, w = tid >> 6, lane = tid & 63;
    int row = blockIdx.x * 4 + w;
    int base = (row >> 10) * NN;
    size_t rb = (size_t)row * MM;

    int jv[MM]; float fltv[MM], corev[MM];
    #pragma unroll
    for (int mm = 0; mm < MM; mm++) jv[mm] = nbr[rb + mm];
    float fsv = fs[row], ysv = ys[(size_t)row * 64 + lane];
    #pragma unroll
    for (int mm = 0; mm < MM; mm++)
        fltv[mm] = filt_l[rb + mm] + fsv + fn[base + jv[mm]];
    #pragma unroll
    for (int mm = 0; mm < MM; mm++)
        corev[mm] = bf2f(core_l[(rb + mm) * 64 + lane]) + ysv
                  + yn[(size_t)(base + jv[mm]) * 64 + lane];
    float fmax = -1e30f;
    #pragma unroll
    for (int mm = 0; mm < MM; mm++) fmax = fmaxf(fmax, fltv[mm]);
    float fsum = 0.f;
    #pragma unroll
    for (int mm = 0; mm < MM; mm++) { fltv[mm] = __expf(fltv[mm] - fmax); fsum += fltv[mm]; }
    float inv = 1.f / (12.f * fsum);
    float summed = 0.f;
    #pragma unroll
    for (int mm = 0; mm < MM; mm++) summed += fltv[mm] * fmaxf(corev[mm], 0.f);
    summed *= inv;
    float o = x[(size_t)row * 64 + lane] + bbg[lane] * (summed * S_BN) + bbb[lane];
    xout[(size_t)row * 64 + lane] = fmaxf(o, 0.f);
}

// ---- pooling gather + dense + relu ----------------------------------------
__global__ __launch_bounds__(256) void final_k(
    const float* __restrict__ x, const int* __restrict__ tidx,
    const float* __restrict__ dw, const float* __restrict__ db,
    float* __restrict__ out) {
    __shared__ float xs[4][64];
    __shared__ float wsh[64 * 64];
    int tid = threadIdx.x;
    int w = tid >> 6, lane = tid & 63;
    const float4* src = (const float4*)dw;
    float4* dst = (float4*)wsh;
    #pragma unroll
    for (int i = 0; i < 4; i++) dst[tid + 256 * i] = src[tid + 256 * i];
    int row = blockIdx.x * 4 + w;        // b*64 + i
    int b = row >> 6;
    int t = tidx[row];
    float xv = x[((size_t)b * NN + t) * 64 + lane];
    xs[w][lane] = fmaxf(xv, 0.f);
    __syncthreads();
    float a = db[lane];
    #pragma unroll 16
    for (int k = 0; k < 64; k++) a += xs[w][k] * wsh[k * 64 + lane];
    out[row * 64 + lane] = fmaxf(a, 0.f);
}

extern "C" void kernel_launch(void* const* d_in, const int* in_sizes, int n_in,
                              void* d_out, int out_size, void* d_ws, size_t ws_size,
                              hipStream_t stream) {
    const int*   at   = (const int*)d_in[0];
    const float* bond = (const float*)d_in[1];
    const int*   nbr  = (const int*)d_in[2];
    const int*   tgt  = (const int*)d_in[3];
    const float* emb  = (const float*)d_in[4];
    const float* cw   = (const float*)d_in[5];
    const float* cb   = (const float*)d_in[6];
    const float* fw   = (const float*)d_in[7];
    const float* fb   = (const float*)d_in[8];
    const float* bag  = (const float*)d_in[9];
    const float* bab  = (const float*)d_in[10];
    const float* bbg  = (const float*)d_in[11];
    const float* bbb  = (const float*)d_in[12];
    const float* dw   = (const float*)d_in[13];
    const float* db   = (const float*)d_in[14];

    float* ws   = (float*)d_ws;
    float* xA   = ws;
    float* xB   = xA + (size_t)BB * NN * FF;          // 1,048,576 each
    float* cwp  = xB + (size_t)BB * NN * FF;          // 49,152
    float* cbp  = cwp + 3 * 256 * 64;                 // 192
    float* ys   = cbp + 192;                          // 1,048,576
    float* yn   = ys + (size_t)BB * NN * FF;          // 1,048,576
    float* fs   = yn + (size_t)BB * NN * FF;          // 16,384
    float* fn   = fs + (size_t)BB * NN;               // 16,384
    float* filt = fn + (size_t)BB * NN;               // 3*196608 fp32
    unsigned short* wT   = (unsigned short*)(filt + 3 * (size_t)RT);  // 28,288 bf16
    unsigned short* core = wT + WCOLS * WSTR;         // 3*196608*64 bf16 (~75.5 MB)
    // total ~95 MB

    fold_w<<<(3 * 256 * 64 + 255) / 256, 256, 0, stream>>>(cw, cb, bag, bab, cwp, cbp);
    prep_wT<<<(WCOLS * WSTR + 255) / 256, 256, 0, stream>>>(cw, bag, fw, wT);
    embed_k<<<(BB * NN * FF) / 256, 256, 0, stream>>>(at, emb, xA);
    gemm_bond<<<512, 256, 0, stream>>>(bond, wT, core, filt);

    float* xin = xA;
    float* xout = xB;
    for (int l = 0; l < 3; l++) {
        atomproj<<<BB * NN / 16, 256, 0, stream>>>(
            xin, cwp + (size_t)l * 256 * 64, cbp + l * 64, fw + l * 256, fb + l,
            ys, yn, fs, fn);
        layer_ep<<<BB * NN / 4, 256, 0, stream>>>(
            xin, core + (size_t)l * RT * 64, filt + (size_t)l * RT, nbr,
            ys, yn, fs, fn, bbg + l * 64, bbb + l * 64, xout);
        float* t = xin; xin = xout; xout = t;
    }

    final_k<<<BB * 64 / 4, 256, 0, stream>>>(xin, tgt, dw, db, (float*)d_out);
}

// Round 3
// 279.872 us; speedup vs baseline: 1.2437x; 1.1405x over previous
//
#include <hip/hip_runtime.h>
#include <hip/hip_bf16.h>

// CGCNN: B=16, N=1024, M=12, F=64, BF=128, 3 conv layers.
// bond is layer-invariant -> ONE bf16 MFMA GEMM produces core+filt for all
// 3 layers. Per-layer: atomproj (x @ [w1|w2|fw1|fw2], now MFMA split-bf16)
// + light gather epilogue (layer_ep).
//
// R1: persistent gemm_bond (weights staged once, barrier-free loop).
// R2: pass-split accs — still spilled ~24 regs (WRITE +36.9MB scratch).
// R3: (a) gemm_bond single 16-row fragment/wave: af[4]+acc[13] ~= 90 live
//     VGPRs, provably spill-free. (b) atomproj VALU GEMV (LDS-bound,
//     ~15-20us/layer) -> MFMA with hi/lo bf16 split (error ~2^-18, keeps
//     absmax at the bond-GEMM's bf16 floor). fs/fn ride along as panel
//     cols 128/129. Panels overlay the dead cwp region (no ws growth).

#define BB 16
#define NN 1024
#define MM 12
#define FF 64
#define BFE 128
#define RT (BB * NN * MM)   // 196608 bond rows
#define S_BN 0.99950037f    // 1/sqrt(1+1e-3)
#define WCOLS 208           // 192 core cols (3 layers x 64) + 3 filt + 13 pad
#define WSTR 136            // padded K stride (bf16) for bond GEMM panel
#define PCOLS 144           // atomproj panel: 64 w1 + 64 w2 + fw1 + fw2 + pad
#define PSTR 72             // padded K stride (bf16) for atomproj panel
#define PSZ (PCOLS * PSTR)  // 10368 shorts per (hi|lo) panel

typedef __attribute__((ext_vector_type(8))) short bf16x8;
typedef __attribute__((ext_vector_type(4))) float f32x4;

static __device__ __forceinline__ unsigned short f2bf(float f) {
    union { float f; unsigned u; } c; c.f = f;
    unsigned r = c.u + 0x7fff + ((c.u >> 16) & 1);   // RNE
    return (unsigned short)(r >> 16);
}
static __device__ __forceinline__ float bf2f(unsigned short s) {
    union { unsigned u; float f; } c; c.u = ((unsigned)s) << 16;
    return c.f;
}
static __device__ __forceinline__ bf16x8 pack_bf16x8(float4 a, float4 b) {
    union { unsigned u[4]; bf16x8 v; } r;
    r.u[0] = (unsigned)f2bf(a.x) | ((unsigned)f2bf(a.y) << 16);
    r.u[1] = (unsigned)f2bf(a.z) | ((unsigned)f2bf(a.w) << 16);
    r.u[2] = (unsigned)f2bf(b.x) | ((unsigned)f2bf(b.y) << 16);
    r.u[3] = (unsigned)f2bf(b.z) | ((unsigned)f2bf(b.w) << 16);
    return r.v;
}
static __device__ __forceinline__ float4 residual4(float4 v) {
    float4 r;
    r.x = v.x - bf2f(f2bf(v.x));
    r.y = v.y - bf2f(f2bf(v.y));
    r.z = v.z - bf2f(f2bf(v.z));
    r.w = v.w - bf2f(f2bf(v.w));
    return r;
}

// ---- fold BN-a into core bias (cbp); cwp region later reused for wproj -----
__global__ void fold_w(const float* __restrict__ cw, const float* __restrict__ cb,
                       const float* __restrict__ g,  const float* __restrict__ bab,
                       float* __restrict__ cbp) {
    int i = blockIdx.x * 256 + threadIdx.x;           // 3*64
    if (i >= 3 * 64) return;
    int f = i & 63, l = i >> 6;
    float gs = g[l * 64 + f] * S_BN;
    cbp[i] = cb[l * 64 + f] * gs + bab[l * 64 + f];
}

// ---- build transposed bf16 weight panel wT[col][k] for the bond GEMM -------
// Column order is PERMUTED per layer so the GEMM epilogue can store packed
// ushort4: panel col l*64 + p (p = tt*16 + m) holds feature f = 4*m + tt.
// cols 192..194: filt_w rows 128..255 for layer col-192; rest zero pad.
__global__ void prep_wT(const float* __restrict__ cw, const float* __restrict__ g,
                        const float* __restrict__ fw, unsigned short* __restrict__ wT) {
    int i = blockIdx.x * 256 + threadIdx.x;           // WCOLS*WSTR = 28288
    if (i >= WCOLS * WSTR) return;
    int col = i / WSTR, k = i % WSTR;
    float v = 0.f;
    if (k < 128) {
        if (col < 192) {
            int l = col >> 6, p = col & 63;
            int f = ((p & 15) << 2) | (p >> 4);       // 4*m + tt
            v = cw[(l * 256 + 128 + k) * 64 + f] * g[l * 64 + f] * S_BN;
        } else if (col < 195) {
            int l = col - 192;
            v = fw[l * 256 + 128 + k];
        }
    }
    wT[i] = f2bf(v);
}

// ---- build hi/lo split-bf16 panels for atomproj MFMA -----------------------
// wproj[l] = [hi panel 144x72][lo panel 144x72] shorts.
// col 0..63: w1 (self, folded BN-a), 64..127: w2 (nbr, folded), 128: fw self,
// 129: fw nbr, rest zero.
__global__ void prep_wproj(const float* __restrict__ cw, const float* __restrict__ g,
                           const float* __restrict__ fw, unsigned short* __restrict__ wproj) {
    int i = blockIdx.x * 256 + threadIdx.x;           // 3*PSZ = 31104
    if (i >= 3 * PSZ) return;
    int l = i / PSZ;
    int rem = i % PSZ;
    int col = rem / PSTR, k = rem % PSTR;
    float v = 0.f;
    if (k < 64) {
        if (col < 64)
            v = cw[(l * 256 + k) * 64 + col] * g[l * 64 + col] * S_BN;
        else if (col < 128)
            v = cw[(l * 256 + 64 + k) * 64 + (col - 64)] * g[l * 64 + (col - 64)] * S_BN;
        else if (col == 128)
            v = fw[l * 256 + k];
        else if (col == 129)
            v = fw[l * 256 + 64 + k];
    }
    unsigned short hi = f2bf(v);
    wproj[(size_t)l * 2 * PSZ + col * PSTR + k] = hi;
    wproj[(size_t)l * 2 * PSZ + PSZ + col * PSTR + k] = f2bf(v - bf2f(hi));
}

// ---- embedding gather ------------------------------------------------------
__global__ void embed_k(const int* __restrict__ at, const float* __restrict__ emb,
                        float* __restrict__ x) {
    int i = blockIdx.x * 256 + threadIdx.x;
    int f = i & 63;
    int bn = i >> 6;
    x[i] = emb[at[bn] * FF + f];
}

// ---- one-shot bf16 MFMA GEMM: core_{0,1,2} (bf16) + filt_{0,1,2} (fp32) ----
// A = bond (196608 x 128, fp32 -> bf16 in registers), B = wT (128 x 208)
// 512 blocks x 6 iters x 64 rows; weights staged once, no barrier in loop.
// One 16-row fragment per wave per iter: ~90 live VGPRs, no spill.
__global__ __launch_bounds__(256, 2) void gemm_bond(
    const float* __restrict__ bond, const unsigned short* __restrict__ wT,
    unsigned short* __restrict__ core, float* __restrict__ filt) {
    __shared__ unsigned short bsh[WCOLS * WSTR];  // 56576 B weights
    int tid = threadIdx.x;
    int w = tid >> 6, lane = tid & 63;
    int m = lane & 15, quad = lane >> 4;

    // stage weights ONCE (3536 float4)
    const float4* wsrc = (const float4*)wT;
    float4* wdst = (float4*)bsh;
    #pragma unroll
    for (int i = 0; i < 14; i++) {
        int idx = tid + 256 * i;
        if (idx < (WCOLS * WSTR * 2) / 16) wdst[idx] = wsrc[idx];
    }
    __syncthreads();

    #pragma unroll 1
    for (int it = 0; it < 6; it++) {
        int row0 = blockIdx.x * 384 + it * 64;
        const float* abase = bond + (size_t)(row0 + w * 16 + m) * BFE + quad * 8;

        bf16x8 af[4];
        #pragma unroll
        for (int c = 0; c < 4; c++) {
            float4 v0 = *(const float4*)(abase + c * 32);
            float4 v1 = *(const float4*)(abase + c * 32 + 4);
            af[c] = pack_bf16x8(v0, v1);
        }

        f32x4 acc[13];
        #pragma unroll
        for (int t = 0; t < 13; t++) acc[t] = (f32x4){0.f, 0.f, 0.f, 0.f};

        #pragma unroll
        for (int c = 0; c < 4; c++) {
            bf16x8 a = af[c];
            #pragma unroll
            for (int t = 0; t < 13; t++) {
                bf16x8 bfv = *(const bf16x8*)&bsh[(t * 16 + m) * WSTR + c * 32 + quad * 8];
                acc[t] = __builtin_amdgcn_mfma_f32_16x16x32_bf16(a, bfv, acc[t], 0, 0, 0);
            }
        }

        int crow = row0 + w * 16 + quad * 4;
        #pragma unroll
        for (int l = 0; l < 3; l++) {
            #pragma unroll
            for (int r = 0; r < 4; r++) {
                ushort4 h;
                h.x = f2bf(acc[l * 4 + 0][r]);
                h.y = f2bf(acc[l * 4 + 1][r]);
                h.z = f2bf(acc[l * 4 + 2][r]);
                h.w = f2bf(acc[l * 4 + 3][r]);
                *(ushort4*)&core[((size_t)l * RT + crow + r) * 64 + 4 * m] = h;
            }
        }
        if (m < 3) {
            #pragma unroll
            for (int r = 0; r < 4; r++)
                filt[(size_t)m * RT + crow + r] = acc[12][r];
        }
    }
}

// ---- per-atom projections via MFMA (hi/lo split-bf16, ~f32 accuracy) -------
// C = x (16384x64) @ panel (64x144): cols 0..63 ys (+bias), 64..127 yn,
// 128 fs-proj (+fb), 129 fn-proj. acc = Ahi*Bhi + Alo*Bhi + Ahi*Blo.
__global__ __launch_bounds__(256) void atomproj_mfma(
    const float* __restrict__ x, const unsigned short* __restrict__ wproj_l,
    const float* __restrict__ cbp_l, const float* __restrict__ fb_l,
    float* __restrict__ ys, float* __restrict__ yn,
    float* __restrict__ fs, float* __restrict__ fn) {
    __shared__ unsigned short psh[2 * PSZ];   // 41472 B: hi panel then lo panel
    int tid = threadIdx.x, w = tid >> 6, lane = tid & 63;
    int m = lane & 15, quad = lane >> 4;

    const float4* src = (const float4*)wproj_l;
    float4* dst = (float4*)psh;
    #pragma unroll
    for (int i = 0; i < 11; i++) {
        int idx = tid + 256 * i;
        if (idx < (2 * PSZ * 2) / 16) dst[idx] = src[idx];
    }
    __syncthreads();

    int row = blockIdx.x * 64 + w * 16 + m;
    const float* xb = x + (size_t)row * 64 + quad * 8;
    bf16x8 ahi[2], alo[2];
    #pragma unroll
    for (int c = 0; c < 2; c++) {
        float4 v0 = *(const float4*)(xb + c * 32);
        float4 v1 = *(const float4*)(xb + c * 32 + 4);
        ahi[c] = pack_bf16x8(v0, v1);
        alo[c] = pack_bf16x8(residual4(v0), residual4(v1));
    }

    f32x4 acc[9];
    #pragma unroll
    for (int t = 0; t < 9; t++) acc[t] = (f32x4){0.f, 0.f, 0.f, 0.f};

    #pragma unroll
    for (int c = 0; c < 2; c++) {
        #pragma unroll
        for (int t = 0; t < 9; t++) {
            int off = (t * 16 + m) * PSTR + c * 32 + quad * 8;
            bf16x8 bh = *(const bf16x8*)&psh[off];
            bf16x8 bl = *(const bf16x8*)&psh[PSZ + off];
            acc[t] = __builtin_amdgcn_mfma_f32_16x16x32_bf16(ahi[c], bh, acc[t], 0, 0, 0);
            acc[t] = __builtin_amdgcn_mfma_f32_16x16x32_bf16(alo[c], bh, acc[t], 0, 0, 0);
            acc[t] = __builtin_amdgcn_mfma_f32_16x16x32_bf16(ahi[c], bl, acc[t], 0, 0, 0);
        }
    }

    int crow = blockIdx.x * 64 + w * 16 + quad * 4;
    #pragma unroll
    for (int t = 0; t < 4; t++) {
        float bias = cbp_l[t * 16 + m];
        #pragma unroll
        for (int r = 0; r < 4; r++)
            ys[(size_t)(crow + r) * 64 + t * 16 + m] = acc[t][r] + bias;
    }
    #pragma unroll
    for (int t = 4; t < 8; t++) {
        #pragma unroll
        for (int r = 0; r < 4; r++)
            yn[(size_t)(crow + r) * 64 + (t - 4) * 16 + m] = acc[t][r];
    }
    if (m == 0) {
        float fbv = fb_l[0];
        #pragma unroll
        for (int r = 0; r < 4; r++) fs[crow + r] = acc[8][r] + fbv;
    }
    if (m == 1) {
        #pragma unroll
        for (int r = 0; r < 4; r++) fn[crow + r] = acc[8][r];
    }
}

// ---- per-layer epilogue: softmax + weighted mean + BN-b + residual ---------
__global__ __launch_bounds__(256) void layer_ep(
    const float* __restrict__ x, const unsigned short* __restrict__ core_l,
    const float* __restrict__ filt_l, const int* __restrict__ nbr,
    const float* __restrict__ ys, const float* __restrict__ yn,
    const float* __restrict__ fs, const float* __restrict__ fn,
    const float* __restrict__ bbg, const float* __restrict__ bbb,
    float* __restrict__ xout) {
    int tid = threadIdx.x, w = tid >> 6, lane = tid & 63;
    int row = blockIdx.x * 4 + w;
    int base = (row >> 10) * NN;
    size_t rb = (size_t)row * MM;

    int jv[MM]; float fltv[MM], corev[MM];
    #pragma unroll
    for (int mm = 0; mm < MM; mm++) jv[mm] = nbr[rb + mm];
    float fsv = fs[row], ysv = ys[(size_t)row * 64 + lane];
    #pragma unroll
    for (int mm = 0; mm < MM; mm++)
        fltv[mm] = filt_l[rb + mm] + fsv + fn[base + jv[mm]];
    #pragma unroll
    for (int mm = 0; mm < MM; mm++)
        corev[mm] = bf2f(core_l[(rb + mm) * 64 + lane]) + ysv
                  + yn[(size_t)(base + jv[mm]) * 64 + lane];
    float fmax = -1e30f;
    #pragma unroll
    for (int mm = 0; mm < MM; mm++) fmax = fmaxf(fmax, fltv[mm]);
    float fsum = 0.f;
    #pragma unroll
    for (int mm = 0; mm < MM; mm++) { fltv[mm] = __expf(fltv[mm] - fmax); fsum += fltv[mm]; }
    float inv = 1.f / (12.f * fsum);
    float summed = 0.f;
    #pragma unroll
    for (int mm = 0; mm < MM; mm++) summed += fltv[mm] * fmaxf(corev[mm], 0.f);
    summed *= inv;
    float o = x[(size_t)row * 64 + lane] + bbg[lane] * (summed * S_BN) + bbb[lane];
    xout[(size_t)row * 64 + lane] = fmaxf(o, 0.f);
}

// ---- pooling gather + dense + relu ----------------------------------------
__global__ __launch_bounds__(256) void final_k(
    const float* __restrict__ x, const int* __restrict__ tidx,
    const float* __restrict__ dw, const float* __restrict__ db,
    float* __restrict__ out) {
    __shared__ float xs[4][64];
    __shared__ float wsh[64 * 64];
    int tid = threadIdx.x;
    int w = tid >> 6, lane = tid & 63;
    const float4* src = (const float4*)dw;
    float4* dst = (float4*)wsh;
    #pragma unroll
    for (int i = 0; i < 4; i++) dst[tid + 256 * i] = src[tid + 256 * i];
    int row = blockIdx.x * 4 + w;        // b*64 + i
    int b = row >> 6;
    int t = tidx[row];
    float xv = x[((size_t)b * NN + t) * 64 + lane];
    xs[w][lane] = fmaxf(xv, 0.f);
    __syncthreads();
    float a = db[lane];
    #pragma unroll 16
    for (int k = 0; k < 64; k++) a += xs[w][k] * wsh[k * 64 + lane];
    out[row * 64 + lane] = fmaxf(a, 0.f);
}

extern "C" void kernel_launch(void* const* d_in, const int* in_sizes, int n_in,
                              void* d_out, int out_size, void* d_ws, size_t ws_size,
                              hipStream_t stream) {
    const int*   at   = (const int*)d_in[0];
    const float* bond = (const float*)d_in[1];
    const int*   nbr  = (const int*)d_in[2];
    const int*   tgt  = (const int*)d_in[3];
    const float* emb  = (const float*)d_in[4];
    const float* cw   = (const float*)d_in[5];
    const float* cb   = (const float*)d_in[6];
    const float* fw   = (const float*)d_in[7];
    const float* fb   = (const float*)d_in[8];
    const float* bag  = (const float*)d_in[9];
    const float* bab  = (const float*)d_in[10];
    const float* bbg  = (const float*)d_in[11];
    const float* bbb  = (const float*)d_in[12];
    const float* dw   = (const float*)d_in[13];
    const float* db   = (const float*)d_in[14];

    float* ws   = (float*)d_ws;
    float* xA   = ws;
    float* xB   = xA + (size_t)BB * NN * FF;          // 1,048,576 each
    float* cwp  = xB + (size_t)BB * NN * FF;          // 49,152 (reused as wproj)
    float* cbp  = cwp + 3 * 256 * 64;                 // 192
    float* ys   = cbp + 192;                          // 1,048,576
    float* yn   = ys + (size_t)BB * NN * FF;          // 1,048,576
    float* fs   = yn + (size_t)BB * NN * FF;          // 16,384
    float* fn   = fs + (size_t)BB * NN;               // 16,384
    float* filt = fn + (size_t)BB * NN;               // 3*196608 fp32
    unsigned short* wT   = (unsigned short*)(filt + 3 * (size_t)RT);  // 28,288 bf16
    unsigned short* core = wT + WCOLS * WSTR;         // 3*196608*64 bf16 (~75.5 MB)
    unsigned short* wproj = (unsigned short*)cwp;     // 62,208 shorts (fits 49,152 f32)
    // total ~95 MB (unchanged)

    fold_w<<<1, 256, 0, stream>>>(cw, cb, bag, bab, cbp);
    prep_wproj<<<(3 * PSZ + 255) / 256, 256, 0, stream>>>(cw, bag, fw, wproj);
    prep_wT<<<(WCOLS * WSTR + 255) / 256, 256, 0, stream>>>(cw, bag, fw, wT);
    embed_k<<<(BB * NN * FF) / 256, 256, 0, stream>>>(at, emb, xA);
    gemm_bond<<<512, 256, 0, stream>>>(bond, wT, core, filt);

    float* xin = xA;
    float* xout = xB;
    for (int l = 0; l < 3; l++) {
        atomproj_mfma<<<BB * NN / 64, 256, 0, stream>>>(
            xin, wproj + (size_t)l * 2 * PSZ, cbp + l * 64, fb + l,
            ys, yn, fs, fn);
        layer_ep<<<BB * NN / 4, 256, 0, stream>>>(
            xin, core + (size_t)l * RT * 64, filt + (size_t)l * RT, nbr,
            ys, yn, fs, fn, bbg + l * 64, bbb + l * 64, xout);
        float* t = xin; xin = xout; xout = t;
    }

    final_k<<<BB * 64 / 4, 256, 0, stream>>>(xin, tgt, dw, db, (float*)d_out);
}